// Round 3
// baseline (255.522 us; speedup 1.0000x reference)
//
#include <hip/hip_runtime.h>
#include <stdint.h>

#define B_  2
#define S_  768
#define D_  768
#define H_  8
#define DH_ 96

typedef unsigned short ushort_t;
typedef __bf16 bf16x8 __attribute__((ext_vector_type(8)));
typedef float  f32x4  __attribute__((ext_vector_type(4)));

__device__ inline ushort_t f2bf(float f) {
    union { float f; unsigned int u; } v; v.f = f;
    unsigned int u = v.u;
    unsigned int r = u + 0x7fffu + ((u >> 16) & 1u);
    return (ushort_t)(r >> 16);
}
__device__ inline float bf2f(ushort_t u) {
    union { unsigned int i; float f; } c; c.i = ((unsigned int)u) << 16;
    return c.f;
}

// ---------------------------------------------------------------- convert
__global__ __launch_bounds__(256) void k_convert(
        const float* __restrict__ X, const float* __restrict__ Wq,
        const float* __restrict__ Wk, const float* __restrict__ Wv,
        const float* __restrict__ Wo,
        ushort_t* __restrict__ Xb, ushort_t* __restrict__ Wb) {
    const int NX4 = (B_ * S_ * D_) / 4;   // 294912
    const int NW4 = (D_ * D_) / 4;        // 147456
    int i = blockIdx.x * blockDim.x + threadIdx.x;
    float4 v;
    ushort_t* dst;
    if (i < NX4) {
        v = ((const float4*)X)[i];
        dst = Xb + i * 4;
    } else {
        int wi = i - NX4;
        int sel = wi / NW4;
        int off = wi - sel * NW4;
        const float* src = (sel == 0) ? Wq : (sel == 1) ? Wk : (sel == 2) ? Wv : Wo;
        v = ((const float4*)src)[off];
        dst = Wb + wi * 4;
    }
    ushort4 o;
    o.x = f2bf(v.x); o.y = f2bf(v.y); o.z = f2bf(v.z); o.w = f2bf(v.w);
    *(ushort4*)dst = o;
}

// ---------------------------------------------------------------- QKV GEMM, L2-direct
// 128x128 block tile (2x2 waves of 64x64), no LDS, no barriers. A,B frags from
// global (L2-hot). grid (18, 12).
__global__ __launch_bounds__(256) void k_qkv(
        const ushort_t* __restrict__ Xb, const ushort_t* __restrict__ Wb,
        const float* __restrict__ bq, const float* __restrict__ bk,
        const float* __restrict__ bv,
        ushort_t* __restrict__ Qb, ushort_t* __restrict__ Kb,
        ushort_t* __restrict__ Vtb) {
    const int tid = threadIdx.x, lane = tid & 63, w = tid >> 6;
    const int frn = lane & 15, fko = (lane >> 4) * 8, frg4 = (lane >> 4) * 4;
    const int m0 = blockIdx.y * 128 + (w & 1) * 64;
    const int n0 = blockIdx.x * 128 + (w >> 1) * 64;
    const ushort_t* Ap = Xb + (size_t)(m0 + frn) * D_ + fko;
    const ushort_t* Bp = Wb + (size_t)(n0 + frn) * D_ + fko;
    f32x4 acc[4][4];
    #pragma unroll
    for (int i = 0; i < 4; i++)
        #pragma unroll
        for (int j = 0; j < 4; j++) acc[i][j] = (f32x4){0.f, 0.f, 0.f, 0.f};
    #pragma unroll 2
    for (int kt = 0; kt < D_; kt += 32) {
        bf16x8 a[4], b[4];
        #pragma unroll
        for (int mi = 0; mi < 4; mi++)
            a[mi] = *(const bf16x8*)(Ap + (size_t)mi * 16 * D_ + kt);
        #pragma unroll
        for (int ni = 0; ni < 4; ni++)
            b[ni] = *(const bf16x8*)(Bp + (size_t)ni * 16 * D_ + kt);
        #pragma unroll
        for (int mi = 0; mi < 4; mi++)
            #pragma unroll
            for (int ni = 0; ni < 4; ni++)
                acc[mi][ni] = __builtin_amdgcn_mfma_f32_16x16x32_bf16(a[mi], b[ni], acc[mi][ni], 0, 0, 0);
    }
    #pragma unroll
    for (int ni = 0; ni < 4; ni++) {
        int gcol = n0 + ni * 16 + frn;
        int g = gcol / D_, d768 = gcol - g * D_;
        int h = d768 / DH_, d = d768 - h * DH_;
        float bias = (g == 0 ? bq : (g == 1 ? bk : bv))[d768];
        #pragma unroll
        for (int mi = 0; mi < 4; mi++) {
            #pragma unroll
            for (int r = 0; r < 4; r++) {
                int grow = m0 + mi * 16 + frg4 + r;
                int bidx = grow / S_, s = grow - bidx * S_;
                ushort_t ob = f2bf(acc[mi][ni][r] + bias);
                int bh = bidx * H_ + h;
                if (g == 0)      Qb[((size_t)bh * S_ + s) * DH_ + d] = ob;
                else if (g == 1) Kb[((size_t)bh * S_ + s) * DH_ + d] = ob;
                else             Vtb[((size_t)bh * DH_ + d) * S_ + s] = ob;
            }
        }
    }
}

// ---------------------------------------------------------------- qcoef
__global__ __launch_bounds__(256) void k_qcoef(
        const ushort_t* __restrict__ Qb,
        const float* __restrict__ Wd, const float* __restrict__ bd,
        const float* __restrict__ Wa, const float* __restrict__ ba,
        float* __restrict__ qcoef) {
    const int wave = threadIdx.x >> 6, lane = threadIdx.x & 63;
    const int row = blockIdx.x * 4 + wave;
    const ushort_t* q = Qb + (size_t)row * DH_;
    float e0 = bf2f(q[lane]);
    float c0 = e0 * Wd[lane];
    float c1 = e0 * Wa[lane];
    float c2 = e0 * (bd[lane] + ba[lane]);
    if (lane < 32) {
        int d = 64 + lane;
        float e1 = bf2f(q[d]);
        c0 += e1 * Wd[d];
        c1 += e1 * Wa[d];
        c2 += e1 * (bd[d] + ba[d]);
    }
    #pragma unroll
    for (int o = 32; o > 0; o >>= 1) {
        c0 += __shfl_down(c0, o);
        c1 += __shfl_down(c1, o);
        c2 += __shfl_down(c2, o);
    }
    if (lane == 0) {
        qcoef[row * 3 + 0] = c0;
        qcoef[row * 3 + 1] = c1;
        qcoef[row * 3 + 2] = c2;
    }
}

// ---------------------------------------------------------------- fused flash
// block = 32 q-rows x one bh. Full 32x768 scores live in registers (24 f32x4 per
// thread). Exact softmax (shfl_xor + LDS cross-wave). probs written once from
// regs; P -> padded LDS -> barrier-free PV loop with V frags from global.
#define PSLD 776   // 768 + 8 pad: row stride 1552B -> 4-bank row shift, conflict-free
__global__ __launch_bounds__(256, 2) void k_flash(
        const ushort_t* __restrict__ Qb, const ushort_t* __restrict__ Kb,
        const ushort_t* __restrict__ Vtb, const float* __restrict__ qcoef,
        const float* __restrict__ distm, const float* __restrict__ angm,
        const float* __restrict__ mask,
        float* __restrict__ probs, ushort_t* __restrict__ Ctxb) {
    __shared__ __align__(16) ushort_t Ps[32 * PSLD];
    __shared__ float mstat[2][32], lstat[2][32];
    const int bh = blockIdx.y, b = bh >> 3, h = bh & 7;
    const int r0 = blockIdx.x * 32;
    const int tid = threadIdx.x, lane = tid & 63, w = tid >> 6;
    const int frn = lane & 15, fko = (lane >> 4) * 8, frg4 = (lane >> 4) * 4;
    const int rhalf = (w & 1) * 16;          // wave's 16-row half
    const int chalf = (w >> 1) * 384;        // wave's 384-col half
    const int whalf = w >> 1;

    const ushort_t* Qbh = Qb + (size_t)bh * S_ * DH_;
    const ushort_t* Kbh = Kb + (size_t)bh * S_ * DH_;
    const ushort_t* Vbh = Vtb + (size_t)bh * DH_ * S_;

    // ---- phase A: S = Q K^T (24 independent 16x16 col-tiles per wave)
    bf16x8 aq[3];
    {
        const ushort_t* qp = Qbh + (size_t)(r0 + rhalf + frn) * DH_ + fko;
        #pragma unroll
        for (int ks = 0; ks < 3; ks++) aq[ks] = *(const bf16x8*)(qp + ks * 32);
    }
    f32x4 acc[24];
    #pragma unroll 4
    for (int t = 0; t < 24; t++) {
        const ushort_t* kp = Kbh + (size_t)(chalf + t * 16 + frn) * DH_ + fko;
        bf16x8 b0 = *(const bf16x8*)(kp);
        bf16x8 b1 = *(const bf16x8*)(kp + 32);
        bf16x8 b2 = *(const bf16x8*)(kp + 64);
        f32x4 c = (f32x4){0.f, 0.f, 0.f, 0.f};
        c = __builtin_amdgcn_mfma_f32_16x16x32_bf16(aq[0], b0, c, 0, 0, 0);
        c = __builtin_amdgcn_mfma_f32_16x16x32_bf16(aq[1], b1, c, 0, 0, 0);
        c = __builtin_amdgcn_mfma_f32_16x16x32_bf16(aq[2], b2, c, 0, 0, 0);
        acc[t] = c;
    }
    // ---- bias epilogue: s = qk/sqrt(96) + dist*c0 + ang*c1 + c2 + maskbias
    float qc0[4], qc1[4], qc2[4];
    #pragma unroll
    for (int r = 0; r < 4; r++) {
        const float* qp = qcoef + ((size_t)bh * S_ + r0 + rhalf + frg4 + r) * 3;
        qc0[r] = qp[0]; qc1[r] = qp[1]; qc2[r] = qp[2];
    }
    const float isq = 0.10206207261596577f;  // 1/sqrt(96)
    const size_t dbase = ((size_t)b * S_ + r0 + rhalf + frg4) * S_;
    #pragma unroll 4
    for (int t = 0; t < 24; t++) {
        int j = chalf + t * 16 + frn;
        float mb = (1.0f - mask[b * S_ + j]) * -10000.0f;
        #pragma unroll
        for (int r = 0; r < 4; r++) {
            float dist = distm[dbase + (size_t)r * S_ + j];
            float ang  = angm [dbase + (size_t)r * S_ + j];
            acc[t][r] = acc[t][r] * isq + dist * qc0[r] + ang * qc1[r] + qc2[r] + mb;
        }
    }
    // ---- phase B: exact softmax
    float mx[4] = {-1e30f, -1e30f, -1e30f, -1e30f};
    #pragma unroll
    for (int t = 0; t < 24; t++)
        #pragma unroll
        for (int r = 0; r < 4; r++) mx[r] = fmaxf(mx[r], acc[t][r]);
    #pragma unroll
    for (int o = 1; o < 16; o <<= 1)
        #pragma unroll
        for (int r = 0; r < 4; r++) mx[r] = fmaxf(mx[r], __shfl_xor(mx[r], o));
    if (frn == 0)
        #pragma unroll
        for (int r = 0; r < 4; r++) mstat[whalf][rhalf + frg4 + r] = mx[r];
    __syncthreads();
    float mf[4], sum[4] = {0.f, 0.f, 0.f, 0.f};
    #pragma unroll
    for (int r = 0; r < 4; r++) {
        int il = rhalf + frg4 + r;
        mf[r] = fmaxf(mstat[0][il], mstat[1][il]);
    }
    #pragma unroll
    for (int t = 0; t < 24; t++)
        #pragma unroll
        for (int r = 0; r < 4; r++) {
            float e = __expf(acc[t][r] - mf[r]);
            acc[t][r] = e;
            sum[r] += e;
        }
    #pragma unroll
    for (int o = 1; o < 16; o <<= 1)
        #pragma unroll
        for (int r = 0; r < 4; r++) sum[r] += __shfl_xor(sum[r], o);
    if (frn == 0)
        #pragma unroll
        for (int r = 0; r < 4; r++) lstat[whalf][rhalf + frg4 + r] = sum[r];
    __syncthreads();
    float inv[4];
    #pragma unroll
    for (int r = 0; r < 4; r++) {
        int il = rhalf + frg4 + r;
        inv[r] = 1.0f / (lstat[0][il] + lstat[1][il]);
    }
    // ---- write probs (f32, once) + P to padded LDS (bf16)
    float* pout = probs + ((size_t)bh * S_ + r0 + rhalf + frg4) * S_;
    #pragma unroll 4
    for (int t = 0; t < 24; t++) {
        int j = chalf + t * 16 + frn;
        #pragma unroll
        for (int r = 0; r < 4; r++) {
            float p = acc[t][r] * inv[r];
            pout[(size_t)r * S_ + j] = p;
            Ps[(rhalf + frg4 + r) * PSLD + j] = f2bf(p);
        }
    }
    __syncthreads();
    // ---- phase C: O = P V  (barrier-free; V frags from global/L2)
    const int cb = (w >> 1) * 48;
    f32x4 accO[3];
    #pragma unroll
    for (int i = 0; i < 3; i++) accO[i] = (f32x4){0.f, 0.f, 0.f, 0.f};
    #pragma unroll 4
    for (int kt = 0; kt < S_; kt += 32) {
        bf16x8 a = *(const bf16x8*)&Ps[(rhalf + frn) * PSLD + kt + fko];
        #pragma unroll
        for (int nt = 0; nt < 3; nt++) {
            bf16x8 v = *(const bf16x8*)(Vbh + (size_t)(cb + nt * 16 + frn) * S_ + kt + fko);
            accO[nt] = __builtin_amdgcn_mfma_f32_16x16x32_bf16(a, v, accO[nt], 0, 0, 0);
        }
    }
    #pragma unroll
    for (int nt = 0; nt < 3; nt++) {
        int col = cb + nt * 16 + frn;
        #pragma unroll
        for (int r = 0; r < 4; r++) {
            int row = r0 + rhalf + frg4 + r;
            Ctxb[((size_t)(b * S_ + row)) * D_ + h * DH_ + col] = f2bf(accO[nt][r]);
        }
    }
}

// ---------------------------------------------------------------- out GEMM, L2-direct
// 64x64 block (2x2 waves of 32x32), no LDS/barriers. grid (12, 24).
__global__ __launch_bounds__(256) void k_out(
        const ushort_t* __restrict__ Ctxb, const ushort_t* __restrict__ Wob,
        const float* __restrict__ bo, const float* __restrict__ hidden,
        float* __restrict__ xbuf) {
    const int tid = threadIdx.x, lane = tid & 63, w = tid >> 6;
    const int frn = lane & 15, fko = (lane >> 4) * 8, frg4 = (lane >> 4) * 4;
    const int m0 = blockIdx.y * 64 + (w & 1) * 32;
    const int n0 = blockIdx.x * 64 + (w >> 1) * 32;
    const ushort_t* Ap = Ctxb + (size_t)(m0 + frn) * D_ + fko;
    const ushort_t* Bp = Wob + (size_t)(n0 + frn) * D_ + fko;
    f32x4 acc[2][2];
    #pragma unroll
    for (int i = 0; i < 2; i++)
        #pragma unroll
        for (int j = 0; j < 2; j++) acc[i][j] = (f32x4){0.f, 0.f, 0.f, 0.f};
    #pragma unroll 4
    for (int kt = 0; kt < D_; kt += 32) {
        bf16x8 a[2], b[2];
        #pragma unroll
        for (int mi = 0; mi < 2; mi++)
            a[mi] = *(const bf16x8*)(Ap + (size_t)mi * 16 * D_ + kt);
        #pragma unroll
        for (int ni = 0; ni < 2; ni++)
            b[ni] = *(const bf16x8*)(Bp + (size_t)ni * 16 * D_ + kt);
        #pragma unroll
        for (int mi = 0; mi < 2; mi++)
            #pragma unroll
            for (int ni = 0; ni < 2; ni++)
                acc[mi][ni] = __builtin_amdgcn_mfma_f32_16x16x32_bf16(a[mi], b[ni], acc[mi][ni], 0, 0, 0);
    }
    #pragma unroll
    for (int ni = 0; ni < 2; ni++) {
        int gcol = n0 + ni * 16 + frn;
        float bias = bo[gcol];
        #pragma unroll
        for (int mi = 0; mi < 2; mi++) {
            #pragma unroll
            for (int r = 0; r < 4; r++) {
                int grow = m0 + mi * 16 + frg4 + r;
                xbuf[(size_t)grow * D_ + gcol] =
                    acc[mi][ni][r] + bias + hidden[(size_t)grow * D_ + gcol];
            }
        }
    }
}

// ---------------------------------------------------------------- LayerNorm
__global__ __launch_bounds__(256) void k_ln(
        const float* __restrict__ xbuf, const float* __restrict__ g,
        const float* __restrict__ bb, float* __restrict__ out) {
    const float* x = xbuf + (size_t)blockIdx.x * D_;
    const int t = threadIdx.x;
    float a0 = x[t], a1 = x[t + 256], a2 = x[t + 512];
    float s = a0 + a1 + a2;
    float ss = a0 * a0 + a1 * a1 + a2 * a2;
    __shared__ float r1[4], r2[4];
    #pragma unroll
    for (int o = 32; o > 0; o >>= 1) { s += __shfl_down(s, o); ss += __shfl_down(ss, o); }
    if ((t & 63) == 0) { r1[t >> 6] = s; r2[t >> 6] = ss; }
    __syncthreads();
    float ts = r1[0] + r1[1] + r1[2] + r1[3];
    float tss = r2[0] + r2[1] + r2[2] + r2[3];
    float mu = ts * (1.0f / D_);
    float var = tss * (1.0f / D_) - mu * mu;
    float rstd = rsqrtf(var + 1e-5f);
    float* o = out + (size_t)blockIdx.x * D_;
    o[t]       = (a0 - mu) * rstd * g[t]       + bb[t];
    o[t + 256] = (a1 - mu) * rstd * g[t + 256] + bb[t + 256];
    o[t + 512] = (a2 - mu) * rstd * g[t + 512] + bb[t + 512];
}

// ---------------------------------------------------------------- launch
extern "C" void kernel_launch(void* const* d_in, const int* in_sizes, int n_in,
                              void* d_out, int out_size, void* d_ws, size_t ws_size,
                              hipStream_t stream) {
    const float* X     = (const float*)d_in[0];
    const float* distm = (const float*)d_in[1];
    const float* angm  = (const float*)d_in[2];
    const float* mask  = (const float*)d_in[3];
    const float* Wq    = (const float*)d_in[4];
    const float* bq    = (const float*)d_in[5];
    const float* Wk    = (const float*)d_in[6];
    const float* bk    = (const float*)d_in[7];
    const float* Wv    = (const float*)d_in[8];
    const float* bv    = (const float*)d_in[9];
    const float* Wd    = (const float*)d_in[10];
    const float* bd    = (const float*)d_in[11];
    const float* Wa    = (const float*)d_in[12];
    const float* ba    = (const float*)d_in[13];
    const float* Wo    = (const float*)d_in[14];
    const float* bo    = (const float*)d_in[15];
    const float* ln_g  = (const float*)d_in[16];
    const float* ln_b  = (const float*)d_in[17];

    float* outp  = (float*)d_out;                        // [B,S,D]
    float* probs = (float*)d_out + (size_t)B_ * S_ * D_; // [B,H,S,S]

    char* ws = (char*)d_ws;
    ushort_t* Xb    = (ushort_t*)(ws + 0);          // 2,359,296 B
    ushort_t* Wb    = (ushort_t*)(ws + 2359296);    // 4,718,592 B
    ushort_t* Qb    = (ushort_t*)(ws + 7077888);    // 2,359,296 B
    ushort_t* Kb    = (ushort_t*)(ws + 9437184);    // 2,359,296 B
    ushort_t* Vtb   = (ushort_t*)(ws + 11796480);   // 2,359,296 B
    ushort_t* Ctxb  = (ushort_t*)(ws + 14155776);   // 2,359,296 B
    float*    qcoef = (float*)   (ws + 16515072);   //   147,456 B
    float*    xbuf  = (float*)   (ws + 16662528);   // 4,718,592 B (end ~21.4 MB)

    k_convert<<<3456, 256, 0, stream>>>(X, Wq, Wk, Wv, Wo, Xb, Wb);
    k_qkv<<<dim3(18, 12), 256, 0, stream>>>(Xb, Wb, bq, bk, bv, Qb, Kb, Vtb);
    k_qcoef<<<3072, 256, 0, stream>>>(Qb, Wd, bd, Wa, ba, qcoef);
    k_flash<<<dim3(24, 16), 256, 0, stream>>>(Qb, Kb, Vtb, qcoef, distm, angm, mask, probs, Ctxb);
    k_out<<<dim3(12, 24), 256, 0, stream>>>(Ctxb, Wb + (size_t)2304 * 768, bo, X, xbuf);
    k_ln<<<1536, 256, 0, stream>>>(xbuf, ln_g, ln_b, outp);
}

// Round 4
// 180.846 us; speedup vs baseline: 1.4129x; 1.4129x over previous
//
#include <hip/hip_runtime.h>
#include <stdint.h>

#define B_  2
#define S_  768
#define D_  768
#define H_  8
#define DH_ 96

typedef unsigned short ushort_t;
typedef __bf16 bf16x8 __attribute__((ext_vector_type(8)));
typedef float  f32x4  __attribute__((ext_vector_type(4)));

__device__ inline ushort_t f2bf(float f) {
    union { float f; unsigned int u; } v; v.f = f;
    unsigned int u = v.u;
    unsigned int r = u + 0x7fffu + ((u >> 16) & 1u);
    return (ushort_t)(r >> 16);
}
__device__ inline float bf2f(ushort_t u) {
    union { unsigned int i; float f; } c; c.i = ((unsigned int)u) << 16;
    return c.f;
}

// async global->LDS, 16B per lane; LDS dest is wave-uniform base + lane*16
__device__ inline void glds16(const void* gp, void* lp) {
    auto g = reinterpret_cast<const __attribute__((address_space(1))) uint32_t*>(
        reinterpret_cast<uintptr_t>(gp));
    auto l = reinterpret_cast<__attribute__((address_space(3))) uint32_t*>(
        reinterpret_cast<uintptr_t>(lp));
    __builtin_amdgcn_global_load_lds(g, l, 16, 0, 0);
}

// ---------------------------------------------------------------- convert
__global__ __launch_bounds__(256) void k_convert(
        const float* __restrict__ X, const float* __restrict__ Wq,
        const float* __restrict__ Wk, const float* __restrict__ Wv,
        const float* __restrict__ Wo,
        ushort_t* __restrict__ Xb, ushort_t* __restrict__ Wb) {
    const int NX4 = (B_ * S_ * D_) / 4;   // 294912
    const int NW4 = (D_ * D_) / 4;        // 147456
    int i = blockIdx.x * blockDim.x + threadIdx.x;
    float4 v;
    ushort_t* dst;
    if (i < NX4) {
        v = ((const float4*)X)[i];
        dst = Xb + i * 4;
    } else {
        int wi = i - NX4;
        int sel = wi / NW4;
        int off = wi - sel * NW4;
        const float* src = (sel == 0) ? Wq : (sel == 1) ? Wk : (sel == 2) ? Wv : Wo;
        v = ((const float4*)src)[off];
        dst = Wb + wi * 4;
    }
    ushort4 o;
    o.x = f2bf(v.x); o.y = f2bf(v.y); o.z = f2bf(v.z); o.w = f2bf(v.w);
    *(ushort4*)dst = o;
}

// ---------------------------------------------------------------- 64x64 GEMM, glds staging
// C = A * Bt^T ; A [M,K] bf16 (lda), Bt [N,K] bf16 (ldb). 256 thr = 4 waves 2x2,
// wave does 2x2 mfma 16x16x32. LDS tiles row-major [64][32].
__device__ inline void gemm64_glds(
        const ushort_t* __restrict__ A, int lda,
        const ushort_t* __restrict__ Bt, int ldb,
        int K, int m0, int n0,
        ushort_t* As, ushort_t* Bs, f32x4 acc[2][2]) {
    const int tid  = threadIdx.x;
    const int lane = tid & 63, wave = tid >> 6;
    const int wm = (wave >> 1) * 32, wn = (wave & 1) * 32;
    const int fr = lane & 15, fk = (lane >> 4) * 8;
    const int sr = wave * 16 + (lane >> 2);     // staging row 0..63
    const int sc = (lane & 3) * 8;              // staging col {0,8,16,24}
    const ushort_t* Ap = A  + (size_t)(m0 + sr) * lda + sc;
    const ushort_t* Bp = Bt + (size_t)(n0 + sr) * ldb + sc;
    ushort_t* AsW = As + wave * 512;
    ushort_t* BsW = Bs + wave * 512;
    for (int kt = 0; kt < K; kt += 32) {
        if (kt) __syncthreads();
        glds16(Ap + kt, AsW);
        glds16(Bp + kt, BsW);
        __syncthreads();
        bf16x8 a0 = *(const bf16x8*)&As[(wm      + fr) * 32 + fk];
        bf16x8 a1 = *(const bf16x8*)&As[(wm + 16 + fr) * 32 + fk];
        bf16x8 b0 = *(const bf16x8*)&Bs[(wn      + fr) * 32 + fk];
        bf16x8 b1 = *(const bf16x8*)&Bs[(wn + 16 + fr) * 32 + fk];
        acc[0][0] = __builtin_amdgcn_mfma_f32_16x16x32_bf16(a0, b0, acc[0][0], 0, 0, 0);
        acc[0][1] = __builtin_amdgcn_mfma_f32_16x16x32_bf16(a0, b1, acc[0][1], 0, 0, 0);
        acc[1][0] = __builtin_amdgcn_mfma_f32_16x16x32_bf16(a1, b0, acc[1][0], 0, 0, 0);
        acc[1][1] = __builtin_amdgcn_mfma_f32_16x16x32_bf16(a1, b1, acc[1][1], 0, 0, 0);
    }
}

// ---------------------------------------------------------------- QKV GEMM
__global__ __launch_bounds__(256) void k_qkv(
        const ushort_t* __restrict__ Xb, const ushort_t* __restrict__ Wb,
        const float* __restrict__ bq, const float* __restrict__ bk,
        const float* __restrict__ bv,
        ushort_t* __restrict__ Qb, ushort_t* __restrict__ Kb,
        ushort_t* __restrict__ Vtb) {
    __shared__ __align__(16) ushort_t As[64 * 32];
    __shared__ __align__(16) ushort_t Bs[64 * 32];
    f32x4 acc[2][2];
    #pragma unroll
    for (int i = 0; i < 2; i++)
        #pragma unroll
        for (int j = 0; j < 2; j++) acc[i][j] = (f32x4){0.f, 0.f, 0.f, 0.f};
    const int m0 = blockIdx.y * 64, n0 = blockIdx.x * 64;
    gemm64_glds(Xb, D_, Wb, D_, D_, m0, n0, As, Bs, acc);
    const int lane = threadIdx.x & 63, wave = threadIdx.x >> 6;
    const int wm = (wave >> 1) * 32, wn = (wave & 1) * 32;
    #pragma unroll
    for (int ni = 0; ni < 2; ni++) {
        int gcol = n0 + wn + ni * 16 + (lane & 15);
        int g = gcol / D_, d768 = gcol - g * D_;
        int h = d768 / DH_, d = d768 - h * DH_;
        float bias = (g == 0 ? bq : (g == 1 ? bk : bv))[d768];
        #pragma unroll
        for (int mi = 0; mi < 2; mi++) {
            #pragma unroll
            for (int r = 0; r < 4; r++) {
                int grow = m0 + wm + mi * 16 + (lane >> 4) * 4 + r;
                int b = grow / S_, s = grow - b * S_;
                ushort_t ob = f2bf(acc[mi][ni][r] + bias);
                int bh = b * H_ + h;
                if (g == 0)      Qb[((size_t)bh * S_ + s) * DH_ + d] = ob;
                else if (g == 1) Kb[((size_t)bh * S_ + s) * DH_ + d] = ob;
                else             Vtb[((size_t)bh * DH_ + d) * S_ + s] = ob;
            }
        }
    }
}

// ---------------------------------------------------------------- qcoef
__global__ __launch_bounds__(256) void k_qcoef(
        const ushort_t* __restrict__ Qb,
        const float* __restrict__ Wd, const float* __restrict__ bd,
        const float* __restrict__ Wa, const float* __restrict__ ba,
        float* __restrict__ qcoef) {
    const int wave = threadIdx.x >> 6, lane = threadIdx.x & 63;
    const int row = blockIdx.x * 4 + wave;
    const ushort_t* q = Qb + (size_t)row * DH_;
    float e0 = bf2f(q[lane]);
    float c0 = e0 * Wd[lane];
    float c1 = e0 * Wa[lane];
    float c2 = e0 * (bd[lane] + ba[lane]);
    if (lane < 32) {
        int d = 64 + lane;
        float e1 = bf2f(q[d]);
        c0 += e1 * Wd[d];
        c1 += e1 * Wa[d];
        c2 += e1 * (bd[d] + ba[d]);
    }
    #pragma unroll
    for (int o = 32; o > 0; o >>= 1) {
        c0 += __shfl_down(c0, o);
        c1 += __shfl_down(c1, o);
        c2 += __shfl_down(c2, o);
    }
    if (lane == 0) {
        qcoef[row * 3 + 0] = c0;
        qcoef[row * 3 + 1] = c1;
        qcoef[row * 3 + 2] = c2;
    }
}

// ---------------------------------------------------------------- fused flash v2
// 1D grid 384, XCD-pinned: idx = h*48 + (b*24 + r0t); 48%8==0 so all 8 heads of a
// (b,r0) tile hit the same XCD -> dist/ang L2 reuse. Per block: 32 q-rows, one bh.
// Loop1: 12 chunks of 64 cols, LDS-staged K/dist/ang (dbuf, 1 barrier/chunk).
// Softmax exact in regs. Loop2: 24 steps of 32 cols, LDS-staged V + Ps32 transpose
// tile; probs written float4-coalesced from Ps32.
#define L1B 29696   // Ks 12288 + Dd 8704 + Da 8704
__global__ __launch_bounds__(256) void k_flash(
        const ushort_t* __restrict__ Qb, const ushort_t* __restrict__ Kb,
        const ushort_t* __restrict__ Vtb, const float* __restrict__ qcoef,
        const float* __restrict__ distm, const float* __restrict__ angm,
        const float* __restrict__ mask,
        float* __restrict__ probs, ushort_t* __restrict__ Ctxb) {
    __shared__ __align__(16) char sm[2 * L1B + 640];
    float* mstat = (float*)(sm + 2 * L1B);          // [2][32]
    float* lstat = (float*)(sm + 2 * L1B + 256);    // [2][32]
    float* linv  = (float*)(sm + 2 * L1B + 512);    // [32]
    const int idx = blockIdx.x;
    const int h = idx / 48, rem = idx - h * 48;
    const int b = rem / 24, r0 = (rem - b * 24) * 32;
    const int bh = b * H_ + h;
    const int tid = threadIdx.x, lane = tid & 63, w = tid >> 6;
    const int frn = lane & 15, fko = (lane >> 4) * 8, frg4 = (lane >> 4) * 4;
    const int rg = w & 1, cp = w >> 1;
    const ushort_t* Qbh = Qb + (size_t)bh * S_ * DH_;
    const ushort_t* Kbh = Kb + (size_t)bh * S_ * DH_;
    const ushort_t* Vbh = Vtb + (size_t)bh * DH_ * S_;

    // Q fragments (one 16-row group per wave)
    bf16x8 aq[3];
    {
        const ushort_t* qp = Qbh + (size_t)(r0 + rg * 16 + frn) * DH_ + fko;
        aq[0] = *(const bf16x8*)qp;
        aq[1] = *(const bf16x8*)(qp + 32);
        aq[2] = *(const bf16x8*)(qp + 64);
    }
    float qc0[4], qc1[4], qc2[4];
    #pragma unroll
    for (int r = 0; r < 4; r++) {
        const float* qp = qcoef + ((size_t)bh * S_ + r0 + rg * 16 + frg4 + r) * 3;
        qc0[r] = qp[0]; qc1[r] = qp[1]; qc2[r] = qp[2];
    }
    const float isq = 0.10206207261596577f;   // 1/sqrt(96)

    // ---- loop 1: scores in regs
    f32x4 acc[24];
    #pragma unroll
    for (int c = 0; c < 12; ++c) {
        char* bufc = sm + (c & 1) * L1B;
        ushort_t* Ks = (ushort_t*)bufc;            // [64][96]
        float* Dd = (float*)(bufc + 12288);        // [32][68]
        float* Da = (float*)(bufc + 20992);        // [32][68]
        #pragma unroll
        for (int k = 0; k < 3; ++k) {
            int i = tid + 256 * k;
            int row = i / 12, cc = (i - row * 12) * 8;
            *(uint4*)(Ks + row * 96 + cc) =
                *(const uint4*)(Kbh + (size_t)(c * 64 + row) * DH_ + cc);
        }
        #pragma unroll
        for (int k = 0; k < 2; ++k) {
            int i = tid + 256 * k;
            int row = i >> 4, c4 = (i & 15) * 4;
            size_t src = ((size_t)b * S_ + r0 + row) * S_ + c * 64 + c4;
            *(float4*)(Dd + row * 68 + c4) = *(const float4*)(distm + src);
            *(float4*)(Da + row * 68 + c4) = *(const float4*)(angm + src);
        }
        __syncthreads();
        #pragma unroll
        for (int tt = 0; tt < 2; ++tt) {
            const ushort_t* kp = Ks + (cp * 32 + tt * 16 + frn) * 96 + fko;
            f32x4 ca = (f32x4){0.f, 0.f, 0.f, 0.f};
            ca = __builtin_amdgcn_mfma_f32_16x16x32_bf16(aq[0], *(const bf16x8*)kp, ca, 0, 0, 0);
            ca = __builtin_amdgcn_mfma_f32_16x16x32_bf16(aq[1], *(const bf16x8*)(kp + 32), ca, 0, 0, 0);
            ca = __builtin_amdgcn_mfma_f32_16x16x32_bf16(aq[2], *(const bf16x8*)(kp + 64), ca, 0, 0, 0);
            int jl = cp * 32 + tt * 16 + frn;
            float mb = (1.0f - mask[b * S_ + c * 64 + jl]) * -10000.0f;
            #pragma unroll
            for (int r = 0; r < 4; ++r) {
                int rl = rg * 16 + frg4 + r;
                acc[c * 2 + tt][r] = ca[r] * isq + Dd[rl * 68 + jl] * qc0[r]
                                   + Da[rl * 68 + jl] * qc1[r] + qc2[r] + mb;
            }
        }
    }
    // ---- softmax (exact)
    float mx[4] = {-1e30f, -1e30f, -1e30f, -1e30f};
    #pragma unroll
    for (int t = 0; t < 24; t++)
        #pragma unroll
        for (int r = 0; r < 4; r++) mx[r] = fmaxf(mx[r], acc[t][r]);
    #pragma unroll
    for (int o = 1; o < 16; o <<= 1)
        #pragma unroll
        for (int r = 0; r < 4; r++) mx[r] = fmaxf(mx[r], __shfl_xor(mx[r], o));
    if (frn == 0)
        #pragma unroll
        for (int r = 0; r < 4; r++) mstat[cp * 32 + rg * 16 + frg4 + r] = mx[r];
    __syncthreads();
    float mf[4], sum[4] = {0.f, 0.f, 0.f, 0.f};
    #pragma unroll
    for (int r = 0; r < 4; r++) {
        int rl = rg * 16 + frg4 + r;
        mf[r] = fmaxf(mstat[rl], mstat[32 + rl]);
    }
    #pragma unroll
    for (int t = 0; t < 24; t++)
        #pragma unroll
        for (int r = 0; r < 4; r++) {
            float e = __expf(acc[t][r] - mf[r]);
            acc[t][r] = e;
            sum[r] += e;
        }
    #pragma unroll
    for (int o = 1; o < 16; o <<= 1)
        #pragma unroll
        for (int r = 0; r < 4; r++) sum[r] += __shfl_xor(sum[r], o);
    if (frn == 0)
        #pragma unroll
        for (int r = 0; r < 4; r++) lstat[cp * 32 + rg * 16 + frg4 + r] = sum[r];
    __syncthreads();
    float inv[4];
    #pragma unroll
    for (int r = 0; r < 4; r++) {
        int rl = rg * 16 + frg4 + r;
        inv[r] = 1.0f / (lstat[rl] + lstat[32 + rl]);
        if (cp == 0 && frn == 0) linv[rl] = inv[r];
    }
    __syncthreads();
    // ---- loop 2: probs write + P@V
    f32x4 accO[3];
    #pragma unroll
    for (int i = 0; i < 3; i++) accO[i] = (f32x4){0.f, 0.f, 0.f, 0.f};
    const int prow = tid >> 3, pc8 = (tid & 7) * 4;
    float* pout = probs + ((size_t)bh * S_ + r0 + prow) * S_;
    const int vrow = tid >> 2, vcv = (tid & 3) * 8;
    const int vrow2 = (tid + 256) >> 2, vcv2 = ((tid + 256) & 3) * 8;
    #pragma unroll
    for (int s = 0; s < 24; ++s) {
        ushort_t* Vs = (ushort_t*)(sm + (s & 1) * 7680);            // [96][40]
        ushort_t* Ps = (ushort_t*)(sm + 15360 + (s & 1) * 2560);    // [32][40]
        *(uint4*)(Vs + vrow * 40 + vcv) =
            *(const uint4*)(Vbh + (size_t)vrow * S_ + s * 32 + vcv);
        if (tid + 256 < 384)
            *(uint4*)(Vs + vrow2 * 40 + vcv2) =
                *(const uint4*)(Vbh + (size_t)vrow2 * S_ + s * 32 + vcv2);
        if (cp == (s & 1)) {
            #pragma unroll
            for (int tt = 0; tt < 2; ++tt)
                #pragma unroll
                for (int r = 0; r < 4; ++r)
                    Ps[(rg * 16 + frg4 + r) * 40 + tt * 16 + frn] =
                        f2bf(acc[(s & ~1) + tt][r]);
        }
        __syncthreads();
        {
            float iv = linv[prow];
            float4 p4;
            p4.x = bf2f(Ps[prow * 40 + pc8 + 0]) * iv;
            p4.y = bf2f(Ps[prow * 40 + pc8 + 1]) * iv;
            p4.z = bf2f(Ps[prow * 40 + pc8 + 2]) * iv;
            p4.w = bf2f(Ps[prow * 40 + pc8 + 3]) * iv;
            *(float4*)(pout + s * 32 + pc8) = p4;
        }
        bf16x8 a = *(const bf16x8*)&Ps[(rg * 16 + frn) * 40 + fko];
        #pragma unroll
        for (int nt = 0; nt < 3; ++nt) {
            bf16x8 v = *(const bf16x8*)&Vs[(cp * 48 + nt * 16 + frn) * 40 + fko];
            accO[nt] = __builtin_amdgcn_mfma_f32_16x16x32_bf16(a, v, accO[nt], 0, 0, 0);
        }
    }
    // ---- ctx epilogue
    #pragma unroll
    for (int nt = 0; nt < 3; ++nt) {
        int col = h * DH_ + cp * 48 + nt * 16 + frn;
        #pragma unroll
        for (int r = 0; r < 4; ++r) {
            int row = r0 + rg * 16 + frg4 + r;
            Ctxb[((size_t)(b * S_ + row)) * D_ + col] = f2bf(accO[nt][r] * inv[r]);
        }
    }
}

// ---------------------------------------------------------------- out GEMM + bias + residual
__global__ __launch_bounds__(256) void k_out(
        const ushort_t* __restrict__ Ctxb, const ushort_t* __restrict__ Wob,
        const float* __restrict__ bo, const float* __restrict__ hidden,
        float* __restrict__ xbuf) {
    __shared__ __align__(16) ushort_t As[64 * 32];
    __shared__ __align__(16) ushort_t Bs[64 * 32];
    f32x4 acc[2][2];
    #pragma unroll
    for (int i = 0; i < 2; i++)
        #pragma unroll
        for (int j = 0; j < 2; j++) acc[i][j] = (f32x4){0.f, 0.f, 0.f, 0.f};
    const int m0 = blockIdx.y * 64, n0 = blockIdx.x * 64;
    gemm64_glds(Ctxb, D_, Wob, D_, D_, m0, n0, As, Bs, acc);
    const int lane = threadIdx.x & 63, wave = threadIdx.x >> 6;
    const int wm = (wave >> 1) * 32, wn = (wave & 1) * 32;
    #pragma unroll
    for (int ni = 0; ni < 2; ni++) {
        int gcol = n0 + wn + ni * 16 + (lane & 15);
        float bias = bo[gcol];
        #pragma unroll
        for (int mi = 0; mi < 2; mi++) {
            #pragma unroll
            for (int r = 0; r < 4; r++) {
                int grow = m0 + wm + mi * 16 + (lane >> 4) * 4 + r;
                xbuf[(size_t)grow * D_ + gcol] =
                    acc[mi][ni][r] + bias + hidden[(size_t)grow * D_ + gcol];
            }
        }
    }
}

// ---------------------------------------------------------------- LayerNorm
__global__ __launch_bounds__(256) void k_ln(
        const float* __restrict__ xbuf, const float* __restrict__ g,
        const float* __restrict__ bb, float* __restrict__ out) {
    const float* x = xbuf + (size_t)blockIdx.x * D_;
    const int t = threadIdx.x;
    float a0 = x[t], a1 = x[t + 256], a2 = x[t + 512];
    float s = a0 + a1 + a2;
    float ss = a0 * a0 + a1 * a1 + a2 * a2;
    __shared__ float r1[4], r2[4];
    #pragma unroll
    for (int o = 32; o > 0; o >>= 1) { s += __shfl_down(s, o); ss += __shfl_down(ss, o); }
    if ((t & 63) == 0) { r1[t >> 6] = s; r2[t >> 6] = ss; }
    __syncthreads();
    float ts = r1[0] + r1[1] + r1[2] + r1[3];
    float tss = r2[0] + r2[1] + r2[2] + r2[3];
    float mu = ts * (1.0f / D_);
    float var = tss * (1.0f / D_) - mu * mu;
    float rstd = rsqrtf(var + 1e-5f);
    float* o = out + (size_t)blockIdx.x * D_;
    o[t]       = (a0 - mu) * rstd * g[t]       + bb[t];
    o[t + 256] = (a1 - mu) * rstd * g[t + 256] + bb[t + 256];
    o[t + 512] = (a2 - mu) * rstd * g[t + 512] + bb[t + 512];
}

// ---------------------------------------------------------------- launch
extern "C" void kernel_launch(void* const* d_in, const int* in_sizes, int n_in,
                              void* d_out, int out_size, void* d_ws, size_t ws_size,
                              hipStream_t stream) {
    const float* X     = (const float*)d_in[0];
    const float* distm = (const float*)d_in[1];
    const float* angm  = (const float*)d_in[2];
    const float* mask  = (const float*)d_in[3];
    const float* Wq    = (const float*)d_in[4];
    const float* bq    = (const float*)d_in[5];
    const float* Wk    = (const float*)d_in[6];
    const float* bk    = (const float*)d_in[7];
    const float* Wv    = (const float*)d_in[8];
    const float* bv    = (const float*)d_in[9];
    const float* Wd    = (const float*)d_in[10];
    const float* bd    = (const float*)d_in[11];
    const float* Wa    = (const float*)d_in[12];
    const float* ba    = (const float*)d_in[13];
    const float* Wo    = (const float*)d_in[14];
    const float* bo    = (const float*)d_in[15];
    const float* ln_g  = (const float*)d_in[16];
    const float* ln_b  = (const float*)d_in[17];

    float* outp  = (float*)d_out;                        // [B,S,D]
    float* probs = (float*)d_out + (size_t)B_ * S_ * D_; // [B,H,S,S]

    char* ws = (char*)d_ws;
    ushort_t* Xb    = (ushort_t*)(ws + 0);          // 2,359,296 B
    ushort_t* Wb    = (ushort_t*)(ws + 2359296);    // 4,718,592 B
    ushort_t* Qb    = (ushort_t*)(ws + 7077888);    // 2,359,296 B
    ushort_t* Kb    = (ushort_t*)(ws + 9437184);    // 2,359,296 B
    ushort_t* Vtb   = (ushort_t*)(ws + 11796480);   // 2,359,296 B
    ushort_t* Ctxb  = (ushort_t*)(ws + 14155776);   // 2,359,296 B
    float*    qcoef = (float*)   (ws + 16515072);   //   147,456 B
    float*    xbuf  = (float*)   (ws + 16662528);   // 4,718,592 B (end ~21.4 MB)

    k_convert<<<3456, 256, 0, stream>>>(X, Wq, Wk, Wv, Wo, Xb, Wb);
    k_qkv<<<dim3(36, 24), 256, 0, stream>>>(Xb, Wb, bq, bk, bv, Qb, Kb, Vtb);
    k_qcoef<<<3072, 256, 0, stream>>>(Qb, Wd, bd, Wa, ba, qcoef);
    k_flash<<<384, 256, 0, stream>>>(Qb, Kb, Vtb, qcoef, distm, angm, mask, probs, Ctxb);
    k_out<<<dim3(12, 24), 256, 0, stream>>>(Ctxb, Wb + (size_t)2304 * 768, bo, X, xbuf);
    k_ln<<<1536, 256, 0, stream>>>(xbuf, ln_g, ln_b, outp);
}